// Round 7
// baseline (682.241 us; speedup 1.0000x reference)
//
#include <hip/hip_runtime.h>
#include <hip/hip_bf16.h>
#include <math.h>

#define N_ROWS 65536
#define P_DIM  256
#define C_DIM  3
#define U_DIM  512
#define NPLANES 7
#define PLANE_STRIDE (U_DIM * P_DIM)   // 131072 elements per bf16 plane

#define BM 128
#define BU 64
#define NUT (U_DIM / BU)               // 8 u-tiles, persistent per block

typedef __attribute__((ext_vector_type(8))) short short8;     // 8 bf16 = 4 VGPR
typedef __attribute__((ext_vector_type(4))) float f32x4;
typedef __attribute__((ext_vector_type(4))) float floatx4;
typedef __attribute__((ext_vector_type(2))) unsigned int uint2v;

static __device__ __forceinline__ unsigned short f2bf(float f) {
    unsigned int u = __builtin_bit_cast(unsigned int, f);
    u += 0x7FFFu + ((u >> 16) & 1u);      // RNE
    return (unsigned short)(u >> 16);
}

// E[relu(N(m, v))]; exact relu when v == 0.
// Division/sqrt-free, Phi via Zelen-Severo poly reusing g = phi(w):
//   s*(g + w*Phi) = s*g + m*Phi ;  Phi(|w|) = 1 - g*poly(t), t = 1/(1+0.2316419|w|)
static __device__ __forceinline__ float erl(float m, float v) {
    float r = __frsqrt_rn(fmaxf(v, 1e-20f));
    float w = m * r;
    float s = v * r;
    float g = __expf(-0.5f * w * w) * 0.3989422804014327f;       // phi(w), even in w
    float aw = fabsf(w);
    float t = __frcp_rn(1.0f + 0.2316419f * aw);
    float poly = t * (0.319381530f + t * (-0.356563782f + t * (1.781477937f
               + t * (-1.821255978f + t * 1.330274429f))));
    float Phi_pos = 1.0f - g * poly;
    float phi = (w >= 0.0f) ? Phi_pos : 1.0f - Phi_pos;
    float val = s * g + m * phi;
    return (v > 0.0f) ? val : fmaxf(m, 0.0f);
}

// ---------------- prep: build B planes (bf16, [plane][u][k] k-contiguous) + tables ----
// plane 0      : kernel[k][u]
// plane 1+c    : mu[k][c]   * kernel[k][u]
// plane 4+c    : var[k][c]  * kernel[k][u]^2
__global__ __launch_bounds__(512) void prep_kernel(
    const float* __restrict__ cmeans, const float* __restrict__ cvars,
    const float* __restrict__ kern, unsigned short* __restrict__ Bt,
    float* __restrict__ inv2v, float* __restrict__ logZ)
{
    int tid = blockIdx.x * 512 + threadIdx.x;
    const int TOTAL_B = NPLANES * PLANE_STRIDE;   // 917504
    if (tid < TOTAL_B) {
        int pl  = tid >> 17;
        int rem = tid & (PLANE_STRIDE - 1);
        int u   = rem >> 8;
        int k   = rem & (P_DIM - 1);
        float kv = kern[k * U_DIM + u];
        float val;
        if (pl == 0)      val = kv;
        else if (pl <= 3) val = cmeans[k * C_DIM + (pl - 1)] * kv;
        else              val = cvars[k * C_DIM + (pl - 4)] * (kv * kv);
        Bt[tid] = f2bf(val);
    } else if (tid - TOTAL_B < P_DIM * C_DIM) {
        int t = tid - TOTAL_B;
        float v = cvars[t];
        inv2v[t] = 0.5f / v;
        logZ[t]  = 0.5f * logf(2.0f * 3.14159265359f * v);
    }
}

// load 7 B-plane fragments for k-step ksi into slot regs (imm-offset folded loads)
#define LOADB(dst, ksi) do {                                                  \
    _Pragma("unroll")                                                         \
    for (int pl = 0; pl < NPLANES; ++pl)                                      \
        dst[pl] = *(const short8*)(bpl[pl] + (ksi) * 32);                     \
} while (0)

// one k-step: 8 LDS A-reads + 28 MFMAs using B slot `breg`
#define STEP(breg, ksi) do {                                                  \
    int kx = ((ksi) * 32 + 8 * lk) ^ swz;                                     \
    _Pragma("unroll")                                                         \
    for (int r = 0; r < 4; ++r) {                                             \
        short8 a0 = *(const short8*)&xs[baseA + r * 4096 + kx];               \
        short8 a1 = *(const short8*)&mk[baseA + r * 4096 + kx];               \
        acc[0][r] = __builtin_amdgcn_mfma_f32_16x16x32_bf16(a0, breg[0], acc[0][r], 0, 0, 0); \
        _Pragma("unroll")                                                     \
        for (int pl = 1; pl < NPLANES; ++pl)                                  \
            acc[pl][r] = __builtin_amdgcn_mfma_f32_16x16x32_bf16(a1, breg[pl], acc[pl][r], 0, 0, 0); \
    }                                                                         \
} while (0)

// ---------------- main: stage X once, fused loglik+softmax, 8 persistent u-tiles ----
// 512 threads = 8 waves (2 row-halves x 4 col-groups); each wave: 64 rows x 16 cols.
// ks fully unrolled with a 3-slot rotating B buffer: prefetch distance 2 STEPs
// (~380 issue cycles) covers L2 latency; slot WAR reuse bounds live range by
// construction (peak ~ acc112 + B84 + A16 + bases14 + addr < 256-reg budget).
__global__ __launch_bounds__(512, 2) void main_kernel(
    const float* __restrict__ X, const unsigned short* __restrict__ Bt,
    const float* __restrict__ cmeans, const float* __restrict__ inv2v,
    const float* __restrict__ logZ, const float* __restrict__ logits,
    const float* __restrict__ bias, float* __restrict__ out)
{
    __shared__ unsigned short xs[BM * P_DIM];   // x_safe bf16, swizzled  (64 KB)
    __shared__ unsigned short mk[BM * P_DIM];   // mask   bf16, swizzled  (64 KB)
    __shared__ float pws[BM][3];                // softmax weights        (1.5 KB)

    const int tid = threadIdx.x;
    const int n0 = blockIdx.x * BM;

    // ---- stage x tile [128][256] fp32 -> x_safe/mask bf16 in LDS (swizzled) ----
    {
        const floatx4* Xv = (const floatx4*)(X + (size_t)n0 * P_DIM);
#pragma unroll
        for (int j = 0; j < 16; ++j) {
            int f = tid + j * 512;            // 8192 float4 total
            floatx4 v = Xv[f];
            int row   = f >> 6;
            int kbase = (f & 63) << 2;
            int idx = row * 256 + (kbase ^ ((row & 7) << 3));
            float e0 = v[0], e1 = v[1], e2 = v[2], e3 = v[3];
            bool na0 = !(e0 == e0), na1 = !(e1 == e1), na2 = !(e2 == e2), na3 = !(e3 == e3);
            unsigned short s0 = na0 ? (unsigned short)0 : f2bf(e0);
            unsigned short s1 = na1 ? (unsigned short)0 : f2bf(e1);
            unsigned short s2 = na2 ? (unsigned short)0 : f2bf(e2);
            unsigned short s3 = na3 ? (unsigned short)0 : f2bf(e3);
            unsigned short m0 = na0 ? (unsigned short)0x3F80 : (unsigned short)0;
            unsigned short m1 = na1 ? (unsigned short)0x3F80 : (unsigned short)0;
            unsigned short m2 = na2 ? (unsigned short)0x3F80 : (unsigned short)0;
            unsigned short m3 = na3 ? (unsigned short)0x3F80 : (unsigned short)0;
            uint2v sp = { (unsigned int)s0 | ((unsigned int)s1 << 16),
                          (unsigned int)s2 | ((unsigned int)s3 << 16) };
            uint2v mp = { (unsigned int)m0 | ((unsigned int)m1 << 16),
                          (unsigned int)m2 | ((unsigned int)m3 << 16) };
            *(uint2v*)&xs[idx] = sp;
            *(uint2v*)&mk[idx] = mp;
        }
    }

    // ---- fused loglik + softmax: 4 threads per row -> pws[row][3] ----
    {
        int row = tid >> 2;
        int sub = tid & 3;
        const floatx4* xr = (const floatx4*)(X + (size_t)(n0 + row) * P_DIM);
        float a0 = 0.f, a1 = 0.f, a2 = 0.f;
#pragma unroll
        for (int i = 0; i < 16; ++i) {
            floatx4 v = xr[sub * 16 + i];
#pragma unroll
            for (int e = 0; e < 4; ++e) {
                float x = v[e];
                int p = sub * 64 + i * 4 + e;
                bool valid = (x == x);
                float xv = valid ? x : 0.f;
                int b = p * 3;
                float d0 = xv - cmeans[b + 0];
                float d1 = xv - cmeans[b + 1];
                float d2 = xv - cmeans[b + 2];
                float q0 = d0 * d0 * inv2v[b + 0] + logZ[b + 0];
                float q1 = d1 * d1 * inv2v[b + 1] + logZ[b + 1];
                float q2 = d2 * d2 * inv2v[b + 2] + logZ[b + 2];
                if (valid) { a0 += q0; a1 += q1; a2 += q2; }
            }
        }
#pragma unroll
        for (int off = 1; off < 4; off <<= 1) {
            a0 += __shfl_xor(a0, off);
            a1 += __shfl_xor(a1, off);
            a2 += __shfl_xor(a2, off);
        }
        if (sub == 0) {
            float z0 = logits[0] - a0;
            float z1 = logits[1] - a1;
            float z2 = logits[2] - a2;
            float mx = fmaxf(z0, fmaxf(z1, z2));
            float e0 = __expf(z0 - mx), e1 = __expf(z1 - mx), e2 = __expf(z2 - mx);
            float inv = 1.0f / (e0 + e1 + e2);
            pws[row][0] = e0 * inv;
            pws[row][1] = e1 * inv;
            pws[row][2] = e2 * inv;
        }
    }
    __syncthreads();

    // ---- persistent u-loop: 3-slot pipelined k-loop MFMA + expected_relu epilogue ----
    const int lane = tid & 63;
    const int wid  = tid >> 6;     // 0..7
    const int wr   = wid >> 2;     // 0..1 : 64-row half
    const int wc   = wid & 3;      // 0..3 : 16-col group
    const int l15  = lane & 15;
    const int lk   = lane >> 4;    // 0..3 : k-block of 8

    const int rowA  = wr * 64 + l15;          // frag r adds r*16 rows
    const int swz   = (rowA & 7) << 3;        // row&7 invariant across frags (r*16)
    const int baseA = rowA * 256;             // + r*4096 elems per frag
    const int colk  = (wc * 16 + l15) * P_DIM + 8 * lk;   // per-lane elem offset in a u-tile plane

#pragma unroll 1
    for (int ut = 0; ut < NUT; ++ut) {
        // per-plane base pointers: every B-load below folds ks*64B into the imm offset
        const unsigned short* bpl[NPLANES];
#pragma unroll
        for (int pl = 0; pl < NPLANES; ++pl)
            bpl[pl] = Bt + (size_t)ut * (BU * P_DIM) + colk + (size_t)pl * PLANE_STRIDE;

        f32x4 acc[NPLANES][4];
#pragma unroll
        for (int pl = 0; pl < NPLANES; ++pl)
#pragma unroll
            for (int r = 0; r < 4; ++r)
                acc[pl][r] = (f32x4){0.f, 0.f, 0.f, 0.f};

        short8 sl0[NPLANES], sl1[NPLANES], sl2[NPLANES];
        // prefetch distance 2: LOAD(ks+2) issued before STEP(ks); slot WAR bounds hoisting
        LOADB(sl0, 0);
        LOADB(sl1, 1);
        LOADB(sl2, 2);  STEP(sl0, 0);
        LOADB(sl0, 3);  STEP(sl1, 1);
        LOADB(sl1, 4);  STEP(sl2, 2);
        LOADB(sl2, 5);  STEP(sl0, 3);
        LOADB(sl0, 6);  STEP(sl1, 4);
        LOADB(sl1, 7);  STEP(sl2, 5);
                        STEP(sl0, 6);
                        STEP(sl1, 7);

        // epilogue: D lane map col = lane&15, row = 4*(lane>>4)+q (+ r*16 + wr*64)
        const int ucol = ut * BU + wc * 16 + l15;
        const float bias_u = bias[ucol];
#pragma unroll
        for (int r = 0; r < 4; ++r) {
            int rloc = wr * 64 + r * 16 + 4 * lk;
#pragma unroll
            for (int q = 0; q < 4; ++q) {
                int rl = rloc + q;
                float p0 = pws[rl][0], p1 = pws[rl][1], p2 = pws[rl][2];
                float y0 = acc[0][r][q] + bias_u;
                float res = p0 * erl(y0 + acc[1][r][q], acc[4][r][q])
                          + p1 * erl(y0 + acc[2][r][q], acc[5][r][q])
                          + p2 * erl(y0 + acc[3][r][q], acc[6][r][q]);
                out[(size_t)(n0 + rl) * U_DIM + ucol] = res;
            }
        }
    }
}

extern "C" void kernel_launch(void* const* d_in, const int* in_sizes, int n_in,
                              void* d_out, int out_size, void* d_ws, size_t ws_size,
                              hipStream_t stream)
{
    const float* X      = (const float*)d_in[0];
    const float* cmeans = (const float*)d_in[1];
    const float* cvars  = (const float*)d_in[2];
    const float* logits = (const float*)d_in[3];
    const float* kern   = (const float*)d_in[4];
    const float* bias   = (const float*)d_in[5];
    float* out = (float*)d_out;

    char* wsb = (char*)d_ws;
    unsigned short* Bt = (unsigned short*)wsb;                 // 1,835,008 B
    float* inv2v = (float*)(wsb + 1835008);                    //     3,072 B
    float* logZ  = (float*)(wsb + 1835008 + 3072);             //     3,072 B

    hipLaunchKernelGGL(prep_kernel, dim3(1794), dim3(512), 0, stream,
                       cmeans, cvars, kern, Bt, inv2v, logZ);
    hipLaunchKernelGGL(main_kernel, dim3(N_ROWS / BM), dim3(512), 0, stream,
                       X, Bt, cmeans, inv2v, logZ, logits, bias, out);
}

// Round 8
// 376.498 us; speedup vs baseline: 1.8121x; 1.8121x over previous
//
#include <hip/hip_runtime.h>
#include <hip/hip_bf16.h>
#include <math.h>

#define N_ROWS 65536
#define P_DIM  256
#define C_DIM  3
#define U_DIM  512
#define NPLANES 7
#define PLANE_STRIDE (U_DIM * P_DIM)   // 131072 elements per bf16 plane

#define BM 128
#define BU 64
#define NUT (U_DIM / BU)               // 8 u-tiles, persistent per block

typedef __attribute__((ext_vector_type(8))) short short8;     // 8 bf16 = 4 VGPR
typedef __attribute__((ext_vector_type(4))) float f32x4;
typedef __attribute__((ext_vector_type(4))) float floatx4;
typedef __attribute__((ext_vector_type(4))) unsigned int uint4v;

static __device__ __forceinline__ unsigned short f2bf(float f) {
    unsigned int u = __builtin_bit_cast(unsigned int, f);
    u += 0x7FFFu + ((u >> 16) & 1u);      // RNE
    return (unsigned short)(u >> 16);
}

// E[relu(N(m, v))]; exact relu when v == 0.
// Division/sqrt-free, Phi via Zelen-Severo poly reusing g = phi(w):
//   s*(g + w*Phi) = s*g + m*Phi ;  Phi(|w|) = 1 - g*poly(t), t = 1/(1+0.2316419|w|)
static __device__ __forceinline__ float erl(float m, float v) {
    float r = __frsqrt_rn(fmaxf(v, 1e-20f));
    float w = m * r;
    float s = v * r;
    float g = __expf(-0.5f * w * w) * 0.3989422804014327f;       // phi(w), even in w
    float aw = fabsf(w);
    float t = __frcp_rn(1.0f + 0.2316419f * aw);
    float poly = t * (0.319381530f + t * (-0.356563782f + t * (1.781477937f
               + t * (-1.821255978f + t * 1.330274429f))));
    float Phi_pos = 1.0f - g * poly;
    float phi = (w >= 0.0f) ? Phi_pos : 1.0f - Phi_pos;
    float val = s * g + m * phi;
    return (v > 0.0f) ? val : fmaxf(m, 0.0f);
}

// ---------------- prep: build B planes (bf16, [plane][u][k] k-contiguous) + tables ----
// plane 0      : kernel[k][u]
// plane 1+c    : mu[k][c]   * kernel[k][u]
// plane 4+c    : var[k][c]  * kernel[k][u]^2
__global__ __launch_bounds__(512) void prep_kernel(
    const float* __restrict__ cmeans, const float* __restrict__ cvars,
    const float* __restrict__ kern, unsigned short* __restrict__ Bt,
    float* __restrict__ inv2v, float* __restrict__ logZ)
{
    int tid = blockIdx.x * 512 + threadIdx.x;
    const int TOTAL_B = NPLANES * PLANE_STRIDE;   // 917504
    if (tid < TOTAL_B) {
        int pl  = tid >> 17;
        int rem = tid & (PLANE_STRIDE - 1);
        int u   = rem >> 8;
        int k   = rem & (P_DIM - 1);
        float kv = kern[k * U_DIM + u];
        float val;
        if (pl == 0)      val = kv;
        else if (pl <= 3) val = cmeans[k * C_DIM + (pl - 1)] * kv;
        else              val = cvars[k * C_DIM + (pl - 4)] * (kv * kv);
        Bt[tid] = f2bf(val);
    } else if (tid - TOTAL_B < P_DIM * C_DIM) {
        int t = tid - TOTAL_B;
        float v = cvars[t];
        inv2v[t] = 0.5f / v;
        logZ[t]  = 0.5f * logf(2.0f * 3.14159265359f * v);
    }
}

// load 7 B-plane fragments for k-step ksi into slot regs
#define LOADB(dst, ksi) do {                                                  \
    const unsigned short* _b = bp + (ksi) * 32;                               \
    _Pragma("unroll")                                                         \
    for (int pl = 0; pl < NPLANES; ++pl)                                      \
        dst[pl] = *(const short8*)(_b + (size_t)pl * PLANE_STRIDE);           \
} while (0)

// one k-step: 8 contiguous (conflict-free) LDS A-reads + 28 MFMAs using B slot `breg`
// fragment-ordered layout: elem = rowblk*4096 + ks*512 + lk*128 + r16*8
#define STEP(breg, ksi) do {                                                  \
    _Pragma("unroll")                                                         \
    for (int r = 0; r < 4; ++r) {                                             \
        short8 a0 = *(const short8*)&xs[aBase + r * 4096 + (ksi) * 512];      \
        short8 a1 = *(const short8*)&mk[aBase + r * 4096 + (ksi) * 512];      \
        acc[0][r] = __builtin_amdgcn_mfma_f32_16x16x32_bf16(a0, breg[0], acc[0][r], 0, 0, 0); \
        _Pragma("unroll")                                                     \
        for (int pl = 1; pl < NPLANES; ++pl)                                  \
            acc[pl][r] = __builtin_amdgcn_mfma_f32_16x16x32_bf16(a1, breg[pl], acc[pl][r], 0, 0, 0); \
    }                                                                         \
} while (0)

// ---------------- main: stage X once, fused loglik+softmax, 8 persistent u-tiles ----
// 512 threads = 8 waves (2 row-halves x 4 col-groups); each wave: 64 rows x 16 cols.
// R6's proven 2-slot B ping-pong (3-slot spills: arch budget = 256 - 112 acc).
// LDS A is stored fragment-ordered so every wave ds_read_b128 is contiguous 1 KB.
__global__ __launch_bounds__(512, 2) void main_kernel(
    const float* __restrict__ X, const unsigned short* __restrict__ Bt,
    const float* __restrict__ cmeans, const float* __restrict__ inv2v,
    const float* __restrict__ logZ, const float* __restrict__ logits,
    const float* __restrict__ bias, float* __restrict__ out)
{
    __shared__ unsigned short xs[BM * P_DIM];   // x_safe bf16, frag-ordered (64 KB)
    __shared__ unsigned short mk[BM * P_DIM];   // mask   bf16, frag-ordered (64 KB)
    __shared__ float pws[BM][3];                // softmax weights           (1.5 KB)

    const int tid = threadIdx.x;
    const int n0 = blockIdx.x * BM;
    const int lane = tid & 63;
    const int wid  = tid >> 6;     // 0..7
    const int l15  = lane & 15;
    const int lk   = lane >> 4;    // 0..3

    // ---- stage x tile: wave wid owns rowblk=wid (16 rows); lane=(r16,lk) reads
    // float8 at [row=wid*16+l15][k=ks*32+lk*8]; LDS writes contiguous 16B/lane ----
    {
        const float* Xb = X + (size_t)(n0 + wid * 16 + l15) * P_DIM + lk * 8;
        const int ebase = ((wid * 8) * 4 + lk) * 128 + l15 * 8;   // + ks*512
#pragma unroll
        for (int ks = 0; ks < 8; ++ks) {
            floatx4 v0 = *(const floatx4*)(Xb + ks * 32);
            floatx4 v1 = *(const floatx4*)(Xb + ks * 32 + 4);
            unsigned int wx[4], wm[4];
#pragma unroll
            for (int h = 0; h < 2; ++h) {
                floatx4 v = h ? v1 : v0;
#pragma unroll
                for (int e = 0; e < 2; ++e) {
                    float f0 = v[2 * e], f1 = v[2 * e + 1];
                    bool na0 = !(f0 == f0), na1 = !(f1 == f1);
                    unsigned int s0 = na0 ? 0u : (unsigned int)f2bf(f0);
                    unsigned int s1 = na1 ? 0u : (unsigned int)f2bf(f1);
                    unsigned int m0 = na0 ? 0x3F80u : 0u;
                    unsigned int m1 = na1 ? 0x3F80u : 0u;
                    wx[h * 2 + e] = s0 | (s1 << 16);
                    wm[h * 2 + e] = m0 | (m1 << 16);
                }
            }
            uint4v px = {wx[0], wx[1], wx[2], wx[3]};
            uint4v pm = {wm[0], wm[1], wm[2], wm[3]};
            *(uint4v*)&xs[ebase + ks * 512] = px;
            *(uint4v*)&mk[ebase + ks * 512] = pm;
        }
    }

    // ---- fused loglik + softmax: 4 threads per row -> pws[row][3] ----
    {
        int row = tid >> 2;
        int sub = tid & 3;
        const floatx4* xr = (const floatx4*)(X + (size_t)(n0 + row) * P_DIM);
        float a0 = 0.f, a1 = 0.f, a2 = 0.f;
#pragma unroll
        for (int i = 0; i < 16; ++i) {
            floatx4 v = xr[sub * 16 + i];
#pragma unroll
            for (int e = 0; e < 4; ++e) {
                float x = v[e];
                int p = sub * 64 + i * 4 + e;
                bool valid = (x == x);
                float xv = valid ? x : 0.f;
                int b = p * 3;
                float d0 = xv - cmeans[b + 0];
                float d1 = xv - cmeans[b + 1];
                float d2 = xv - cmeans[b + 2];
                float q0 = d0 * d0 * inv2v[b + 0] + logZ[b + 0];
                float q1 = d1 * d1 * inv2v[b + 1] + logZ[b + 1];
                float q2 = d2 * d2 * inv2v[b + 2] + logZ[b + 2];
                if (valid) { a0 += q0; a1 += q1; a2 += q2; }
            }
        }
#pragma unroll
        for (int off = 1; off < 4; off <<= 1) {
            a0 += __shfl_xor(a0, off);
            a1 += __shfl_xor(a1, off);
            a2 += __shfl_xor(a2, off);
        }
        if (sub == 0) {
            float z0 = logits[0] - a0;
            float z1 = logits[1] - a1;
            float z2 = logits[2] - a2;
            float mx = fmaxf(z0, fmaxf(z1, z2));
            float e0 = __expf(z0 - mx), e1 = __expf(z1 - mx), e2 = __expf(z2 - mx);
            float inv = 1.0f / (e0 + e1 + e2);
            pws[row][0] = e0 * inv;
            pws[row][1] = e1 * inv;
            pws[row][2] = e2 * inv;
        }
    }
    __syncthreads();

    // ---- persistent u-loop: 2-slot pipelined k-loop MFMA + expected_relu epilogue ----
    const int wr   = wid >> 2;     // 0..1 : 64-row half
    const int wc   = wid & 3;      // 0..3 : 16-col group
    // frag r (rows wr*64 + r*16 + l15): rowblk = wr*4 + r
    const int aBase = wr * 16384 + lk * 128 + l15 * 8;    // + r*4096 + ks*512
    const int colk  = (wc * 16 + l15) * P_DIM + 8 * lk;   // per-lane elem offset in a u-tile plane

#pragma unroll 1
    for (int ut = 0; ut < NUT; ++ut) {
        const unsigned short* bp = Bt + (size_t)ut * (BU * P_DIM) + colk;

        f32x4 acc[NPLANES][4];
#pragma unroll
        for (int pl = 0; pl < NPLANES; ++pl)
#pragma unroll
            for (int r = 0; r < 4; ++r)
                acc[pl][r] = (f32x4){0.f, 0.f, 0.f, 0.f};

        short8 bA[NPLANES], bB[NPLANES];
        LOADB(bA, 0);
#pragma unroll 1
        for (int ks = 0; ks < 8; ks += 2) {
            LOADB(bB, ks + 1);          // prefetch odd step
            STEP(bA, ks);               // compute even step
            if (ks + 2 < 8) LOADB(bA, ks + 2);   // prefetch next even step
            STEP(bB, ks + 1);           // compute odd step
        }

        // epilogue: D lane map col = lane&15, row = 4*(lane>>4)+q (+ r*16 + wr*64)
        const int ucol = ut * BU + wc * 16 + l15;
        const float bias_u = bias[ucol];
#pragma unroll
        for (int r = 0; r < 4; ++r) {
            int rloc = wr * 64 + r * 16 + 4 * lk;
#pragma unroll
            for (int q = 0; q < 4; ++q) {
                int rl = rloc + q;
                float p0 = pws[rl][0], p1 = pws[rl][1], p2 = pws[rl][2];
                float y0 = acc[0][r][q] + bias_u;
                float res = p0 * erl(y0 + acc[1][r][q], acc[4][r][q])
                          + p1 * erl(y0 + acc[2][r][q], acc[5][r][q])
                          + p2 * erl(y0 + acc[3][r][q], acc[6][r][q]);
                out[(size_t)(n0 + rl) * U_DIM + ucol] = res;
            }
        }
    }
}

extern "C" void kernel_launch(void* const* d_in, const int* in_sizes, int n_in,
                              void* d_out, int out_size, void* d_ws, size_t ws_size,
                              hipStream_t stream)
{
    const float* X      = (const float*)d_in[0];
    const float* cmeans = (const float*)d_in[1];
    const float* cvars  = (const float*)d_in[2];
    const float* logits = (const float*)d_in[3];
    const float* kern   = (const float*)d_in[4];
    const float* bias   = (const float*)d_in[5];
    float* out = (float*)d_out;

    char* wsb = (char*)d_ws;
    unsigned short* Bt = (unsigned short*)wsb;                 // 1,835,008 B
    float* inv2v = (float*)(wsb + 1835008);                    //     3,072 B
    float* logZ  = (float*)(wsb + 1835008 + 3072);             //     3,072 B

    hipLaunchKernelGGL(prep_kernel, dim3(1794), dim3(512), 0, stream,
                       cmeans, cvars, kern, Bt, inv2v, logZ);
    hipLaunchKernelGGL(main_kernel, dim3(N_ROWS / BM), dim3(512), 0, stream,
                       X, Bt, cmeans, inv2v, logZ, logits, bias, out);
}